// Round 19
// baseline (482.768 us; speedup 1.0000x reference)
//
#include <hip/hip_runtime.h>
#include <hip/hip_fp16.h>

typedef _Float16 half8 __attribute__((ext_vector_type(8)));
typedef float f32x4 __attribute__((ext_vector_type(4)));

#define MFMA16(a, b, c) __builtin_amdgcn_mfma_f32_16x16x32_f16((a), (b), (c), 0, 0, 0)
#define DEVI __device__ __forceinline__

static constexpr int T_ = 128, B_ = 4096, HID_ = 128;
static constexpr int TB_ = T_ * B_;

// ---------------- workspace layout (units: _Float16 elements) ----------------
static constexpr size_t W1P = 0;               // [16nt][1kt][64][8]   = 8192
static constexpr size_t W2P = 8192;            // [16][8][64][8]       = 65536
static constexpr size_t W3P = 73728;           // [8][8][64][8]        = 32768
static constexpr size_t W4P = 106496;          // [1][4][64][8]        = 2048
static constexpr size_t WHL = 108544;          // [32nt][12kt][64][8]  = 196608 (hi kt<6, lo kt>=6)
static constexpr size_t MSGT = 305152;         // [16][16]             = 256
static constexpr size_t HDW = 305408;          // head W [2nt][4kt][64][8] = 4096 (rows 23..31 zero)
static constexpr size_t FEAT = 309504;         // [TB][40] f16
static constexpr size_t WS_HALFS = FEAT + (size_t)TB_ * 40;
// f32 bcomb[512] at byte offset WS_HALFS*2; f32 hb[32] right after

// ---------------- output layout (f32 elements) ----------------
static constexpr size_t OUT_ACT = (size_t)TB_ * 128;
static constexpr size_t OUT_MSG = OUT_ACT + (size_t)TB_ * 6;
static constexpr size_t OUT_VAL = OUT_MSG + (size_t)TB_ * 16;
static constexpr size_t OUT_HN  = OUT_VAL + (size_t)TB_;
static constexpr size_t OUT_CN  = OUT_HN + (size_t)B_ * 128;

// v_rcp_f32-based activations (avoid IEEE div sequences)
DEVI float sigm_(float x) { return __builtin_amdgcn_rcpf(1.f + __expf(-x)); }
DEVI float tanh_(float x) { return 1.f - 2.f * __builtin_amdgcn_rcpf(1.f + __expf(2.f * x)); }

// barrier that drains ONLY LDS ops (no vmcnt): hid stores + prefetch loads
// stay in flight across steps. Proven correct in R4/R8 (absmax 0.0039).
DEVI void lds_barrier() {
    asm volatile("s_waitcnt lgkmcnt(0)" ::: "memory");
    __builtin_amdgcn_s_barrier();
    asm volatile("" ::: "memory");
}

// =============== merged prep: all weight packing in ONE kernel ===============
DEVI void pack_one(const float* __restrict__ src, _Float16* __restrict__ dst,
                   int KT, int srcN, int srcK, int total, int idx) {
    if (idx >= total) return;
    int j = idx & 7, l = (idx >> 3) & 63, rest = idx >> 9;
    int kt = rest % KT, nt = rest / KT;
    int n = nt * 16 + (l & 15);
    int k = kt * 32 + ((l >> 4) << 3) + j;
    float v = (n < srcN && k < srcK) ? src[n * srcK + k] : 0.f;
    dst[idx] = (_Float16)v;
}

__global__ void k_prep(const float* __restrict__ vw1, const float* __restrict__ vw2,
                       const float* __restrict__ vw3, const float* __restrict__ vw4,
                       const float* __restrict__ wih, const float* __restrict__ whh,
                       const float* __restrict__ emb, const float* __restrict__ mw,
                       const float* __restrict__ mb, const float* __restrict__ bih,
                       const float* __restrict__ bhh,
                       const float* __restrict__ aw, const float* __restrict__ ab,
                       const float* __restrict__ cw, const float* __restrict__ cb,
                       const float* __restrict__ msw, const float* __restrict__ msb,
                       _Float16* __restrict__ wsh, float* __restrict__ bcomb) {
    const int blk = blockIdx.x, tid = threadIdx.x;
    if (blk < 768) {
        // combined LSTM weight, hi/lo split f16 (w = hi + lo ~ 22-bit mantissa)
        int idx = blk * 256 + tid;  // 196608 exact
        int j = idx & 7, l = (idx >> 3) & 63, rest = idx >> 9;
        int kt = rest % 12, nt = rest / 12;
        int n = nt * 16 + (l & 15);
        int k = (kt % 6) * 32 + ((l >> 4) << 3) + j;
        float v;
        if (k < 64) v = (k < 36) ? wih[n * 36 + k] : 0.f;
        else        v = whh[n * 128 + (k - 64)];
        float hi = (float)(_Float16)v;
        wsh[WHL + idx] = (kt < 6) ? (_Float16)hi : (_Float16)(v - hi);
    } else if (blk < 800) {
        pack_one(vw1, wsh + W1P, 1, 256, 9, 8192, (blk - 768) * 256 + tid);
    } else if (blk < 1056) {
        pack_one(vw2, wsh + W2P, 8, 256, 256, 65536, (blk - 800) * 256 + tid);
    } else if (blk < 1184) {
        pack_one(vw3, wsh + W3P, 8, 128, 256, 32768, (blk - 1056) * 256 + tid);
    } else if (blk < 1192) {
        pack_one(vw4, wsh + W4P, 4, 16, 128, 2048, (blk - 1184) * 256 + tid);
    } else if (blk == 1192) {
        // message table (16 words x 16 feats)
        int w = tid >> 4, j = tid & 15;
        float a = mb[j];
        for (int e = 0; e < 16; ++e) a += emb[w * 16 + e] * mw[j * 16 + e];
        wsh[MSGT + tid] = (_Float16)fmaxf(a, 0.f);
    } else if (blk < 1195) {
        int i = (blk - 1193) * 256 + tid;  // 512 total
        bcomb[i] = bih[i] + bhh[i];
    } else if (blk < 1211) {
        // head weights [2nt][4kt][64][8]: rows 0..5 aw, 6..21 msw, 22 cw, 23..31 zero
        int idx = (blk - 1195) * 256 + tid;  // 4096 exact
        int j = idx & 7, l = (idx >> 3) & 63, rest = idx >> 9;
        int kt = rest & 3, nt = rest >> 2;
        int n = nt * 16 + (l & 15);
        int k = kt * 32 + ((l >> 4) << 3) + j;
        float v = (n < 6) ? aw[n * 128 + k]
                : (n < 22) ? msw[(n - 6) * 128 + k]
                : (n == 22) ? cw[k] : 0.f;
        wsh[HDW + idx] = (_Float16)v;
    } else {
        // head bias
        if (tid < 32) {
            float* hb = bcomb + 512;
            hb[tid] = (tid < 6) ? ab[tid] : (tid < 22) ? msb[tid - 6]
                    : (tid == 22) ? cb[0] : 0.f;
        }
    }
}

// =============== encoder: 128-row tiles, exclusive nt-ownership per wave ===============
// 4096 blocks x 128 rows, 512 threads (8 waves), 152.5 KB LDS (1 block/CU,
// 2 waves/SIMD — same TLP as R13-best). Each wave owns an EXCLUSIVE nt-range
// so weight L2 traffic halves vs 64-row blocks (1.76 GB -> 0.88 GB); afr is
// re-loaded from LDS per mt (cheap). MFMA orientation / converts / bias forms
// byte-identical to validated R13.
__global__ __attribute__((amdgpu_flat_work_group_size(512, 512)))
__attribute__((amdgpu_waves_per_eu(2, 2)))
void k_encoder(const float* __restrict__ img, const float* __restrict__ loc,
               const int* __restrict__ msg,
               const float* __restrict__ vb1, const float* __restrict__ vb2,
               const float* __restrict__ vb3, const float* __restrict__ vb4,
               const float* __restrict__ lw, const float* __restrict__ lb,
               const _Float16* __restrict__ wsh, _Float16* __restrict__ feat) {
    __shared__ __align__(16) _Float16 sA[128 * 40];    // 10.0 KB
    __shared__ __align__(16) _Float16 sU[128 * 264];   // 66.0 KB
    __shared__ __align__(16) _Float16 sV[128 * 264];   // 66.0 KB
    __shared__ int smsg[128];

    const int tid = threadIdx.x;
    const int lane = tid & 63, w = tid >> 6;           // 8 waves
    const int lq = lane >> 4, lr = lane & 15;
    const int rowbase = blockIdx.x * 128;

    for (int i = tid; i < 1152; i += 512) {            // 128 rows x 9
        int m = i / 9, k = i - m * 9;
        sA[m * 40 + k] = (_Float16)(img[(size_t)rowbase * 9 + i] * (1.f / 255.f));
    }
    for (int i = tid; i < 128 * 32; i += 512) {        // zero K-pad cols 9..40
        int m = i >> 5, k = 9 + (i & 31);
        if (k < 40) sA[m * 40 + k] = (_Float16)0.f;
    }
    if (tid < 128) smsg[tid] = msg[rowbase + tid];
    __syncthreads();

    const half8* w1p = (const half8*)(wsh + W1P);
    const half8* w2p = (const half8*)(wsh + W2P);
    const half8* w3p = (const half8*)(wsh + W3P);
    const half8* w4p = (const half8*)(wsh + W4P);

    // ---- L1: wave owns nt in {2w, 2w+1}; K=9 (1 kt) ----
    {
        half8 bfr0 = w1p[(2 * w + 0) * 64 + lane];
        half8 bfr1 = w1p[(2 * w + 1) * 64 + lane];
        const float b0 = vb1[(2 * w + 0) * 16 + lr];
        const float b1 = vb1[(2 * w + 1) * 16 + lr];
        #pragma unroll
        for (int mt = 0; mt < 8; ++mt) {
            half8 afr = *(const half8*)&sA[(mt * 16 + lr) * 40 + lq * 8];
            f32x4 a0 = (f32x4){0.f, 0.f, 0.f, 0.f};
            f32x4 a1 = (f32x4){0.f, 0.f, 0.f, 0.f};
            a0 = MFMA16(afr, bfr0, a0);
            a1 = MFMA16(afr, bfr1, a1);
            #pragma unroll
            for (int r = 0; r < 4; ++r) {
                sU[(mt * 16 + lq * 4 + r) * 264 + (2 * w + 0) * 16 + lr] =
                    (_Float16)fmaxf(a0[r] + b0, 0.f);
                sU[(mt * 16 + lq * 4 + r) * 264 + (2 * w + 1) * 16 + lr] =
                    (_Float16)fmaxf(a1[r] + b1, 0.f);
            }
        }
    }
    __syncthreads();

    // ---- L2: wave owns nt in {2w, 2w+1}; bfr[2][8] held, afr per mt ----
    {
        half8 bfr[2][8];
        #pragma unroll
        for (int n = 0; n < 2; ++n)
            #pragma unroll
            for (int kt = 0; kt < 8; ++kt)
                bfr[n][kt] = w2p[((2 * w + n) * 8 + kt) * 64 + lane];
        const float b0 = vb2[(2 * w + 0) * 16 + lr];
        const float b1 = vb2[(2 * w + 1) * 16 + lr];
        #pragma unroll
        for (int mt = 0; mt < 8; ++mt) {
            half8 afr[8];
            #pragma unroll
            for (int kt = 0; kt < 8; ++kt)
                afr[kt] = *(const half8*)&sU[(mt * 16 + lr) * 264 + kt * 32 + lq * 8];
            f32x4 a0 = (f32x4){0.f, 0.f, 0.f, 0.f};
            f32x4 a1 = (f32x4){0.f, 0.f, 0.f, 0.f};
            #pragma unroll
            for (int kt = 0; kt < 8; ++kt) {
                a0 = MFMA16(afr[kt], bfr[0][kt], a0);
                a1 = MFMA16(afr[kt], bfr[1][kt], a1);
            }
            #pragma unroll
            for (int r = 0; r < 4; ++r) {
                sV[(mt * 16 + lq * 4 + r) * 264 + (2 * w + 0) * 16 + lr] =
                    (_Float16)fmaxf(a0[r] + b0, 0.f);
                sV[(mt * 16 + lq * 4 + r) * 264 + (2 * w + 1) * 16 + lr] =
                    (_Float16)fmaxf(a1[r] + b1, 0.f);
            }
        }
    }
    __syncthreads();

    // ---- L3: wave owns nt = w (8 nt total); bfr[8] held, afr per mt ----
    {
        half8 bfr[8];
        #pragma unroll
        for (int kt = 0; kt < 8; ++kt)
            bfr[kt] = w3p[(w * 8 + kt) * 64 + lane];
        const float b0 = vb3[w * 16 + lr];
        #pragma unroll
        for (int mt = 0; mt < 8; ++mt) {
            half8 afr[8];
            #pragma unroll
            for (int kt = 0; kt < 8; ++kt)
                afr[kt] = *(const half8*)&sV[(mt * 16 + lr) * 264 + kt * 32 + lq * 8];
            f32x4 a0 = (f32x4){0.f, 0.f, 0.f, 0.f};
            #pragma unroll
            for (int kt = 0; kt < 8; ++kt) a0 = MFMA16(afr[kt], bfr[kt], a0);
            #pragma unroll
            for (int r = 0; r < 4; ++r)
                sU[(mt * 16 + lq * 4 + r) * 264 + w * 16 + lr] =
                    (_Float16)fmaxf(a0[r] + b0, 0.f);
        }
    }
    __syncthreads();

    // ---- L4: wave w owns batch group w (16 rows): sU[16,128] x w4 -> sA cols 0..15 ----
    {
        f32x4 acc = (f32x4){0.f, 0.f, 0.f, 0.f};
        #pragma unroll
        for (int kt = 0; kt < 4; ++kt) {
            half8 b4 = w4p[kt * 64 + lane];
            half8 a4 = *(const half8*)&sU[(w * 16 + lr) * 264 + kt * 32 + lq * 8];
            acc = MFMA16(a4, b4, acc);
        }
        const float bias = vb4[lr];
        #pragma unroll
        for (int r = 0; r < 4; ++r)
            sA[(w * 16 + lq * 4 + r) * 40 + lr] = (_Float16)fmaxf(acc[r] + bias, 0.f);
    }

    // ---- tail: loc (cols 16..19), msg (20..35), zeros (36..39) ----
    {
        int m = tid >> 2, o = tid & 3;                 // 512 threads = 128 rows x 4
        float x0 = loc[(size_t)(rowbase + m) * 2 + 0] * 0.2f;
        float x1 = loc[(size_t)(rowbase + m) * 2 + 1] * 0.2f;
        sA[m * 40 + 16 + o] = (_Float16)(x0 * lw[o * 2 + 0] + x1 * lw[o * 2 + 1] + lb[o]);
    }
    {
        const _Float16* mst = wsh + MSGT;
        for (int f = tid; f < 2048; f += 512) {        // 128 rows x 16
            int m = f >> 4, c = f & 15;
            sA[m * 40 + 20 + c] = mst[smsg[m] * 16 + c];
        }
    }
    {
        int m = tid >> 2, c = 36 + (tid & 3);
        sA[m * 40 + c] = (_Float16)0.f;
    }
    __syncthreads();

    // copy out: 128 rows x 40 halfs = 640 uint4, contiguous both sides
    uint4* dst = (uint4*)(feat + (size_t)rowbase * 40);
    const uint4* srcv = (const uint4*)sA;
    for (int i = tid; i < 640; i += 512) dst[i] = srcv[i];
}

// =============== LSTM: R13 (best measured: 251 us) — UNCHANGED ===============
__global__ __attribute__((amdgpu_flat_work_group_size(512, 512)))
__attribute__((amdgpu_waves_per_eu(2, 2)))
void k_lstm8(const _Float16* __restrict__ wsh, const float* __restrict__ bcomb,
             const float* __restrict__ done, const float* __restrict__ h0,
             const float* __restrict__ c0, float* __restrict__ hid,
             float* __restrict__ hN, float* __restrict__ cN) {
    __shared__ __align__(16) _Float16 sH[2][16 * 136];
    __shared__ __align__(16) _Float16 sX[2][16 * 72];
    __shared__ __align__(16) float sDm[2][16];

    const int tid = threadIdx.x;
    const int w = tid >> 6, lane = tid & 63;
    const int lq = lane >> 4, lr = lane & 15;
    const int b0 = blockIdx.x * 16;
    const int j = w * 16 + lr;
    const _Float16* feat = wsh + FEAT;
    const half8* wlt = (const half8*)(wsh + WHL);

    half8 wfr[4][12];
    #pragma unroll
    for (int g = 0; g < 4; ++g)
        #pragma unroll
        for (int kt = 0; kt < 12; ++kt)
            wfr[g][kt] = wlt[((8 * g + w) * 12 + kt) * 64 + lane];

    float bias[4];
    #pragma unroll
    for (int g = 0; g < 4; ++g) bias[g] = bcomb[g * 128 + j];

    const half8 hz = {0, 0, 0, 0, 0, 0, 0, 0};

    f32x4 cc, hl;
    #pragma unroll
    for (int r = 0; r < 4; ++r) cc[r] = c0[(size_t)(b0 + lq * 4 + r) * 128 + j];

    for (int i = tid; i < 2048; i += 512) {
        int m = i >> 7, k = i & 127;
        sH[0][m * 136 + k] = (_Float16)h0[(size_t)(b0 + m) * 128 + k];
    }
    for (int i = tid; i < 1024; i += 512) {
        int bb = i >> 9, rem = i & 511;
        int m = rem >> 5, c = 40 + (rem & 31);
        sX[bb][m * 72 + c] = (_Float16)0.f;
    }
    const bool stx = tid < 160;
    const int sm = tid / 10, sc = tid - sm * 10;
    if (stx) *(uint2*)(&sX[0][sm * 72 + sc * 4]) =
        *(const uint2*)(feat + (size_t)(b0 + sm) * 40 + sc * 4);
    if (tid < 16) sDm[0][tid] = 1.f - done[b0 + tid];

    uint2 xrA = {0, 0}, xrB = {0, 0};
    float drA = 0.f, drB = 0.f;
    if (stx) xrA = *(const uint2*)(feat + ((size_t)B_ + b0 + sm) * 40 + sc * 4);
    if (tid < 16) drA = done[(size_t)B_ + b0 + tid];

    const _Float16* fptr = feat + ((size_t)2 * B_ + b0 + sm) * 40 + sc * 4;
    const float* dptr = done + (size_t)2 * B_ + b0 + tid;
    float* hq = hid + (size_t)b0 * 128 + j;

    __syncthreads();

    for (int t = 0; t < T_; ++t) {
        const int p = t & 1;
        const bool pf1 = (t + 1 < T_);
        const bool pf2 = (t + 2 < T_);

        if (stx && pf1) *(uint2*)(&sX[1 - p][sm * 72 + sc * 4]) = xrA;
        if (tid < 16 && pf1) sDm[1 - p][tid] = 1.f - drA;

        if (stx && pf2) xrB = *(const uint2*)fptr;
        if (tid < 16 && pf2) drB = dptr[0];
        fptr += (size_t)B_ * 40;
        dptr += B_;

        if (t > 0) {
            #pragma unroll
            for (int r = 0; r < 4; ++r)
                hq[(size_t)(lq * 4 + r) * 128] = hl[r];
            hq += (size_t)B_ * 128;
        }

        const f32x4 dmv = *(const f32x4*)&sDm[p][lq * 4];
        const float dml = sDm[p][lr];
        const bool keep = (dml != 0.f);

        f32x4 acc[4];
        #pragma unroll
        for (int g = 0; g < 4; ++g)
            acc[g] = (f32x4){bias[g], bias[g], bias[g], bias[g]};

        {
            half8 x0 = *(const half8*)&sX[p][lr * 72 + lq * 8];
            half8 x1 = *(const half8*)&sX[p][lr * 72 + 32 + lq * 8];
            #pragma unroll
            for (int g = 0; g < 4; ++g) acc[g] = MFMA16(x0, wfr[g][0], acc[g]);
            #pragma unroll
            for (int g = 0; g < 4; ++g) acc[g] = MFMA16(x0, wfr[g][6], acc[g]);
            #pragma unroll
            for (int g = 0; g < 4; ++g) acc[g] = MFMA16(x1, wfr[g][1], acc[g]);
            #pragma unroll
            for (int g = 0; g < 4; ++g) acc[g] = MFMA16(x1, wfr[g][7], acc[g]);
        }

        #pragma unroll
        for (int u = 0; u < 4; ++u) {
            half8 av = *(const half8*)&sH[p][lr * 136 + u * 32 + lq * 8];
            av = keep ? av : hz;
            #pragma unroll
            for (int g = 0; g < 4; ++g) acc[g] = MFMA16(av, wfr[g][2 + u], acc[g]);
            #pragma unroll
            for (int g = 0; g < 4; ++g) acc[g] = MFMA16(av, wfr[g][8 + u], acc[g]);
        }

        #pragma unroll
        for (int r = 0; r < 4; ++r) {
            const int m = lq * 4 + r;
            float iv = sigm_(acc[0][r]);
            float fv = sigm_(acc[1][r]);
            float gv = tanh_(acc[2][r]);
            float ov = sigm_(acc[3][r]);
            float cn = fv * (cc[r] * dmv[r]) + iv * gv;
            float hv = ov * tanh_(cn);
            cc[r] = cn;
            hl[r] = hv;
            sH[1 - p][m * 136 + j] = (_Float16)hv;
        }

        lds_barrier();
        xrA = xrB;
        drA = drB;
    }

    #pragma unroll
    for (int r = 0; r < 4; ++r) {
        hq[(size_t)(lq * 4 + r) * 128] = hl[r];
        hN[(size_t)(b0 + lq * 4 + r) * 128 + j] = hl[r];
        cN[(size_t)(b0 + lq * 4 + r) * 128 + j] = cc[r];
    }
}

// =============== heads: MFMA (R18-validated) — UNCHANGED ===============
__global__ __launch_bounds__(256)
void k_heads(const float* __restrict__ hidden, const _Float16* __restrict__ wsh,
             const float* __restrict__ bcomb, float* __restrict__ oact,
             float* __restrict__ omsg, float* __restrict__ oval) {
    __shared__ __align__(16) _Float16 sHd[64 * 136];
    const int tid = threadIdx.x;
    const int w = tid >> 6, lane = tid & 63;
    const int lq = lane >> 4, lr = lane & 15;
    const int rowbase = blockIdx.x * 64;

    {
        const int m = tid >> 2, q = tid & 3;
        const float* src = hidden + (size_t)(rowbase + m) * 128 + q * 32;
        #pragma unroll
        for (int s = 0; s < 4; ++s) {
            f32x4 a = *(const f32x4*)(src + s * 8);
            f32x4 b = *(const f32x4*)(src + s * 8 + 4);
            half8 pk;
            #pragma unroll
            for (int e = 0; e < 4; ++e) pk[e] = (_Float16)a[e];
            #pragma unroll
            for (int e = 0; e < 4; ++e) pk[4 + e] = (_Float16)b[e];
            *(half8*)&sHd[m * 136 + q * 32 + s * 8] = pk;
        }
    }
    __syncthreads();

    half8 av[4];
    #pragma unroll
    for (int kt = 0; kt < 4; ++kt)
        av[kt] = *(const half8*)&sHd[(w * 16 + lr) * 136 + kt * 32 + lq * 8];

    const half8* hwp = (const half8*)(wsh + HDW);
    const float* hb = bcomb + 512;
    #pragma unroll
    for (int nt = 0; nt < 2; ++nt) {
        const float b0 = hb[nt * 16 + lr];
        f32x4 hacc = (f32x4){b0, b0, b0, b0};
        #pragma unroll
        for (int kt = 0; kt < 4; ++kt)
            hacc = MFMA16(av[kt], hwp[(nt * 4 + kt) * 64 + lane], hacc);
        const int o = nt * 16 + lr;
        #pragma unroll
        for (int r = 0; r < 4; ++r) {
            const size_t row = (size_t)rowbase + w * 16 + lq * 4 + r;
            float vv = hacc[r];
            if (o < 6)        oact[row * 6 + o] = vv;
            else if (o < 22)  omsg[row * 16 + (o - 6)] = vv;
            else if (o == 22) oval[row] = vv;
        }
    }
}

// =============== launch ===============
extern "C" void kernel_launch(void* const* d_in, const int* in_sizes, int n_in,
                              void* d_out, int out_size, void* d_ws, size_t ws_size,
                              hipStream_t stream) {
    const float* image = (const float*)d_in[0];
    const float* location = (const float*)d_in[1];
    const int*   message = (const int*)d_in[2];
    const float* done = (const float*)d_in[3];
    const float* h0 = (const float*)d_in[4];
    const float* c0 = (const float*)d_in[5];
    const float* vw1 = (const float*)d_in[6];  const float* vb1 = (const float*)d_in[7];
    const float* vw2 = (const float*)d_in[8];  const float* vb2 = (const float*)d_in[9];
    const float* vw3 = (const float*)d_in[10]; const float* vb3 = (const float*)d_in[11];
    const float* vw4 = (const float*)d_in[12]; const float* vb4 = (const float*)d_in[13];
    const float* emb = (const float*)d_in[14];
    const float* mw = (const float*)d_in[15];  const float* mb = (const float*)d_in[16];
    const float* lw = (const float*)d_in[17];  const float* lb = (const float*)d_in[18];
    const float* wih = (const float*)d_in[19]; const float* whh = (const float*)d_in[20];
    const float* bih = (const float*)d_in[21]; const float* bhh = (const float*)d_in[22];
    const float* aw = (const float*)d_in[23];  const float* ab = (const float*)d_in[24];
    const float* cw = (const float*)d_in[25];  const float* cb = (const float*)d_in[26];
    const float* msw = (const float*)d_in[27]; const float* msb = (const float*)d_in[28];

    _Float16* wsh = (_Float16*)d_ws;
    float* bcomb = (float*)((char*)d_ws + WS_HALFS * 2);

    float* out = (float*)d_out;
    float* oh   = out;
    float* oact = out + OUT_ACT;
    float* omsg = out + OUT_MSG;
    float* oval = out + OUT_VAL;
    float* ohN  = out + OUT_HN;
    float* ocN  = out + OUT_CN;

    // merged prep (1 launch)
    k_prep<<<1212, 256, 0, stream>>>(vw1, vw2, vw3, vw4, wih, whh, emb, mw, mb,
                                     bih, bhh, aw, ab, cw, cb, msw, msb,
                                     wsh, bcomb);
    // encoder -> feat f16 [TB,40] (128-row tiles)
    k_encoder<<<TB_ / 128, 512, 0, stream>>>(image, location, message, vb1, vb2, vb3, vb4,
                                             lw, lb, wsh, wsh + FEAT);
    // recurrent scan
    k_lstm8<<<B_ / 16, 512, 0, stream>>>(wsh, bcomb, done, h0, c0, oh, ohN, ocN);
    // heads (MFMA)
    k_heads<<<TB_ / 64, 256, 0, stream>>>(oh, wsh, bcomb, oact, omsg, oval);
}

// Round 20
// 460.126 us; speedup vs baseline: 1.0492x; 1.0492x over previous
//
#include <hip/hip_runtime.h>
#include <hip/hip_fp16.h>

typedef _Float16 half8 __attribute__((ext_vector_type(8)));
typedef float f32x4 __attribute__((ext_vector_type(4)));

#define MFMA16(a, b, c) __builtin_amdgcn_mfma_f32_16x16x32_f16((a), (b), (c), 0, 0, 0)
#define DEVI __device__ __forceinline__

static constexpr int T_ = 128, B_ = 4096, HID_ = 128;
static constexpr int TB_ = T_ * B_;

// ---------------- workspace layout (units: _Float16 elements) ----------------
static constexpr size_t W1P = 0;               // [16nt][1kt][64][8]   = 8192
static constexpr size_t W2P = 8192;            // [16][8][64][8]       = 65536
static constexpr size_t W3P = 73728;           // [8][8][64][8]        = 32768
static constexpr size_t W4P = 106496;          // [1][4][64][8]        = 2048
static constexpr size_t WHL = 108544;          // [32nt][12kt][64][8]  = 196608 (hi kt<6, lo kt>=6)
static constexpr size_t MSGT = 305152;         // [16][16]             = 256
static constexpr size_t HDW = 305408;          // head W [2nt][4kt][64][8] = 4096 (rows 23..31 zero)
static constexpr size_t FEAT = 309504;         // [TB][40] f16
static constexpr size_t WS_HALFS = FEAT + (size_t)TB_ * 40;
// f32 bcomb[512] at byte offset WS_HALFS*2; f32 hb[32] right after

// ---------------- output layout (f32 elements) ----------------
static constexpr size_t OUT_ACT = (size_t)TB_ * 128;
static constexpr size_t OUT_MSG = OUT_ACT + (size_t)TB_ * 6;
static constexpr size_t OUT_VAL = OUT_MSG + (size_t)TB_ * 16;
static constexpr size_t OUT_HN  = OUT_VAL + (size_t)TB_;
static constexpr size_t OUT_CN  = OUT_HN + (size_t)B_ * 128;

// v_rcp_f32-based activations (avoid IEEE div sequences)
DEVI float sigm_(float x) { return __builtin_amdgcn_rcpf(1.f + __expf(-x)); }
DEVI float tanh_(float x) { return 1.f - 2.f * __builtin_amdgcn_rcpf(1.f + __expf(2.f * x)); }

// barrier that drains ONLY LDS ops (no vmcnt): hid stores + prefetch loads
// stay in flight across steps. Proven correct in R4/R8 (absmax 0.0039).
DEVI void lds_barrier() {
    asm volatile("s_waitcnt lgkmcnt(0)" ::: "memory");
    __builtin_amdgcn_s_barrier();
    asm volatile("" ::: "memory");
}

// =============== merged prep: all weight packing in ONE kernel ===============
DEVI void pack_one(const float* __restrict__ src, _Float16* __restrict__ dst,
                   int KT, int srcN, int srcK, int total, int idx) {
    if (idx >= total) return;
    int j = idx & 7, l = (idx >> 3) & 63, rest = idx >> 9;
    int kt = rest % KT, nt = rest / KT;
    int n = nt * 16 + (l & 15);
    int k = kt * 32 + ((l >> 4) << 3) + j;
    float v = (n < srcN && k < srcK) ? src[n * srcK + k] : 0.f;
    dst[idx] = (_Float16)v;
}

__global__ void k_prep(const float* __restrict__ vw1, const float* __restrict__ vw2,
                       const float* __restrict__ vw3, const float* __restrict__ vw4,
                       const float* __restrict__ wih, const float* __restrict__ whh,
                       const float* __restrict__ emb, const float* __restrict__ mw,
                       const float* __restrict__ mb, const float* __restrict__ bih,
                       const float* __restrict__ bhh,
                       const float* __restrict__ aw, const float* __restrict__ ab,
                       const float* __restrict__ cw, const float* __restrict__ cb,
                       const float* __restrict__ msw, const float* __restrict__ msb,
                       _Float16* __restrict__ wsh, float* __restrict__ bcomb) {
    const int blk = blockIdx.x, tid = threadIdx.x;
    if (blk < 768) {
        // combined LSTM weight, hi/lo split f16 (w = hi + lo ~ 22-bit mantissa)
        int idx = blk * 256 + tid;  // 196608 exact
        int j = idx & 7, l = (idx >> 3) & 63, rest = idx >> 9;
        int kt = rest % 12, nt = rest / 12;
        int n = nt * 16 + (l & 15);
        int k = (kt % 6) * 32 + ((l >> 4) << 3) + j;
        float v;
        if (k < 64) v = (k < 36) ? wih[n * 36 + k] : 0.f;
        else        v = whh[n * 128 + (k - 64)];
        float hi = (float)(_Float16)v;
        wsh[WHL + idx] = (kt < 6) ? (_Float16)hi : (_Float16)(v - hi);
    } else if (blk < 800) {
        pack_one(vw1, wsh + W1P, 1, 256, 9, 8192, (blk - 768) * 256 + tid);
    } else if (blk < 1056) {
        pack_one(vw2, wsh + W2P, 8, 256, 256, 65536, (blk - 800) * 256 + tid);
    } else if (blk < 1184) {
        pack_one(vw3, wsh + W3P, 8, 128, 256, 32768, (blk - 1056) * 256 + tid);
    } else if (blk < 1192) {
        pack_one(vw4, wsh + W4P, 4, 16, 128, 2048, (blk - 1184) * 256 + tid);
    } else if (blk == 1192) {
        // message table (16 words x 16 feats)
        int w = tid >> 4, j = tid & 15;
        float a = mb[j];
        for (int e = 0; e < 16; ++e) a += emb[w * 16 + e] * mw[j * 16 + e];
        wsh[MSGT + tid] = (_Float16)fmaxf(a, 0.f);
    } else if (blk < 1195) {
        int i = (blk - 1193) * 256 + tid;  // 512 total
        bcomb[i] = bih[i] + bhh[i];
    } else if (blk < 1211) {
        // head weights [2nt][4kt][64][8]: rows 0..5 aw, 6..21 msw, 22 cw, 23..31 zero
        int idx = (blk - 1195) * 256 + tid;  // 4096 exact
        int j = idx & 7, l = (idx >> 3) & 63, rest = idx >> 9;
        int kt = rest & 3, nt = rest >> 2;
        int n = nt * 16 + (l & 15);
        int k = kt * 32 + ((l >> 4) << 3) + j;
        float v = (n < 6) ? aw[n * 128 + k]
                : (n < 22) ? msw[(n - 6) * 128 + k]
                : (n == 22) ? cw[k] : 0.f;
        wsh[HDW + idx] = (_Float16)v;
    } else {
        // head bias
        if (tid < 32) {
            float* hb = bcomb + 512;
            hb[tid] = (tid < 6) ? ab[tid] : (tid < 22) ? msb[tid - 6]
                    : (tid == 22) ? cb[0] : 0.f;
        }
    }
}

// =============== encoder: R13-exact (best measured config) ===============
__global__ __launch_bounds__(256, 2)
void k_encoder(const float* __restrict__ img, const float* __restrict__ loc,
               const int* __restrict__ msg,
               const float* __restrict__ vb1, const float* __restrict__ vb2,
               const float* __restrict__ vb3, const float* __restrict__ vb4,
               const float* __restrict__ lw, const float* __restrict__ lb,
               const _Float16* __restrict__ wsh, _Float16* __restrict__ feat) {
    __shared__ __align__(16) _Float16 sA[64 * 40];
    __shared__ __align__(16) _Float16 sU[64 * 264];
    __shared__ __align__(16) _Float16 sV[64 * 264];
    __shared__ int smsg[64];

    const int tid = threadIdx.x;
    const int lane = tid & 63, wv = tid >> 6;
    const int lq = lane >> 4, lr = lane & 15;
    const int rowbase = blockIdx.x * 64;

    for (int i = tid; i < 576; i += 256) {
        int m = i / 9, k = i - m * 9;
        sA[m * 40 + k] = (_Float16)(img[(size_t)rowbase * 9 + i] * (1.f / 255.f));
    }
    for (int i = tid; i < 64 * 32; i += 256) {
        int m = i >> 5, k = 9 + (i & 31);
        if (k < 40) sA[m * 40 + k] = (_Float16)0.f;
    }
    if (tid < 64) smsg[tid] = msg[rowbase + tid];
    __syncthreads();

    const half8* w1p = (const half8*)(wsh + W1P);
    const half8* w2p = (const half8*)(wsh + W2P);
    const half8* w3p = (const half8*)(wsh + W3P);
    const half8* w4p = (const half8*)(wsh + W4P);

    // ---- L1 ----
    {
        half8 afr[4];
        #pragma unroll
        for (int mt = 0; mt < 4; ++mt)
            afr[mt] = *(const half8*)&sA[(mt * 16 + lr) * 40 + lq * 8];
        #pragma unroll
        for (int ntl = 0; ntl < 4; ++ntl) {
            const int nt = wv * 4 + ntl;
            half8 bfr = w1p[nt * 64 + lane];
            f32x4 acc[4];
            #pragma unroll
            for (int mt = 0; mt < 4; ++mt) acc[mt] = (f32x4){0.f, 0.f, 0.f, 0.f};
            #pragma unroll
            for (int mt = 0; mt < 4; ++mt) acc[mt] = MFMA16(afr[mt], bfr, acc[mt]);
            const int n = nt * 16 + lr;
            const float bias = vb1[n];
            #pragma unroll
            for (int mt = 0; mt < 4; ++mt)
                #pragma unroll
                for (int r = 0; r < 4; ++r)
                    sU[(mt * 16 + lq * 4 + r) * 264 + n] = (_Float16)fmaxf(acc[mt][r] + bias, 0.f);
        }
    }
    __syncthreads();

    // ---- L2 ----
    {
        half8 afr[4][8];
        #pragma unroll
        for (int mt = 0; mt < 4; ++mt)
            #pragma unroll
            for (int kt = 0; kt < 8; ++kt)
                afr[mt][kt] = *(const half8*)&sU[(mt * 16 + lr) * 264 + kt * 32 + lq * 8];
        #pragma unroll
        for (int ntl = 0; ntl < 4; ++ntl) {
            const int nt = wv * 4 + ntl;
            half8 bfr[8];
            #pragma unroll
            for (int kt = 0; kt < 8; ++kt) bfr[kt] = w2p[(nt * 8 + kt) * 64 + lane];
            f32x4 acc[4];
            #pragma unroll
            for (int mt = 0; mt < 4; ++mt) acc[mt] = (f32x4){0.f, 0.f, 0.f, 0.f};
            #pragma unroll
            for (int kt = 0; kt < 8; ++kt)
                #pragma unroll
                for (int mt = 0; mt < 4; ++mt)
                    acc[mt] = MFMA16(afr[mt][kt], bfr[kt], acc[mt]);
            const int n = nt * 16 + lr;
            const float bias = vb2[n];
            #pragma unroll
            for (int mt = 0; mt < 4; ++mt)
                #pragma unroll
                for (int r = 0; r < 4; ++r)
                    sV[(mt * 16 + lq * 4 + r) * 264 + n] = (_Float16)fmaxf(acc[mt][r] + bias, 0.f);
        }
    }
    __syncthreads();

    // ---- L3 ----
    {
        half8 afr[4][8];
        #pragma unroll
        for (int mt = 0; mt < 4; ++mt)
            #pragma unroll
            for (int kt = 0; kt < 8; ++kt)
                afr[mt][kt] = *(const half8*)&sV[(mt * 16 + lr) * 264 + kt * 32 + lq * 8];
        #pragma unroll
        for (int ntl = 0; ntl < 2; ++ntl) {
            const int nt = wv * 2 + ntl;
            half8 bfr[8];
            #pragma unroll
            for (int kt = 0; kt < 8; ++kt) bfr[kt] = w3p[(nt * 8 + kt) * 64 + lane];
            f32x4 acc[4];
            #pragma unroll
            for (int mt = 0; mt < 4; ++mt) acc[mt] = (f32x4){0.f, 0.f, 0.f, 0.f};
            #pragma unroll
            for (int kt = 0; kt < 8; ++kt)
                #pragma unroll
                for (int mt = 0; mt < 4; ++mt)
                    acc[mt] = MFMA16(afr[mt][kt], bfr[kt], acc[mt]);
            const int n = nt * 16 + lr;
            const float bias = vb3[n];
            #pragma unroll
            for (int mt = 0; mt < 4; ++mt)
                #pragma unroll
                for (int r = 0; r < 4; ++r)
                    sU[(mt * 16 + lq * 4 + r) * 264 + n] = (_Float16)fmaxf(acc[mt][r] + bias, 0.f);
        }
    }
    __syncthreads();

    // ---- L4 ----
    {
        half8 b4[4], a4[4];
        #pragma unroll
        for (int kt = 0; kt < 4; ++kt) {
            b4[kt] = w4p[kt * 64 + lane];
            a4[kt] = *(const half8*)&sU[(wv * 16 + lr) * 264 + kt * 32 + lq * 8];
        }
        f32x4 acc = (f32x4){0.f, 0.f, 0.f, 0.f};
        #pragma unroll
        for (int kt = 0; kt < 4; ++kt) acc = MFMA16(a4[kt], b4[kt], acc);
        const float bias = vb4[lr];
        #pragma unroll
        for (int r = 0; r < 4; ++r)
            sA[(wv * 16 + lq * 4 + r) * 40 + lr] = (_Float16)fmaxf(acc[r] + bias, 0.f);
    }

    // ---- tail: loc / msg / zero ----
    {
        int m = tid >> 2, o = tid & 3;
        float x0 = loc[(size_t)(rowbase + m) * 2 + 0] * 0.2f;
        float x1 = loc[(size_t)(rowbase + m) * 2 + 1] * 0.2f;
        sA[m * 40 + 16 + o] = (_Float16)(x0 * lw[o * 2 + 0] + x1 * lw[o * 2 + 1] + lb[o]);
    }
    {
        const _Float16* mst = wsh + MSGT;
        for (int f = tid; f < 1024; f += 256) {
            int m = f >> 4, c = f & 15;
            sA[m * 40 + 20 + c] = mst[smsg[m] * 16 + c];
        }
    }
    {
        int m = tid >> 2, c = 36 + (tid & 3);
        sA[m * 40 + c] = (_Float16)0.f;
    }
    __syncthreads();

    uint4* dst = (uint4*)(feat + (size_t)rowbase * 40);
    const uint4* srcv = (const uint4*)sA;
    for (int i = tid; i < 320; i += 256) dst[i] = srcv[i];
}

// =============== LSTM: R13 (best measured: 251 us) — UNCHANGED ===============
__global__ __attribute__((amdgpu_flat_work_group_size(512, 512)))
__attribute__((amdgpu_waves_per_eu(2, 2)))
void k_lstm8(const _Float16* __restrict__ wsh, const float* __restrict__ bcomb,
             const float* __restrict__ done, const float* __restrict__ h0,
             const float* __restrict__ c0, float* __restrict__ hid,
             float* __restrict__ hN, float* __restrict__ cN) {
    __shared__ __align__(16) _Float16 sH[2][16 * 136];
    __shared__ __align__(16) _Float16 sX[2][16 * 72];
    __shared__ __align__(16) float sDm[2][16];

    const int tid = threadIdx.x;
    const int w = tid >> 6, lane = tid & 63;
    const int lq = lane >> 4, lr = lane & 15;
    const int b0 = blockIdx.x * 16;
    const int j = w * 16 + lr;
    const _Float16* feat = wsh + FEAT;
    const half8* wlt = (const half8*)(wsh + WHL);

    half8 wfr[4][12];
    #pragma unroll
    for (int g = 0; g < 4; ++g)
        #pragma unroll
        for (int kt = 0; kt < 12; ++kt)
            wfr[g][kt] = wlt[((8 * g + w) * 12 + kt) * 64 + lane];

    float bias[4];
    #pragma unroll
    for (int g = 0; g < 4; ++g) bias[g] = bcomb[g * 128 + j];

    const half8 hz = {0, 0, 0, 0, 0, 0, 0, 0};

    f32x4 cc, hl;
    #pragma unroll
    for (int r = 0; r < 4; ++r) cc[r] = c0[(size_t)(b0 + lq * 4 + r) * 128 + j];

    for (int i = tid; i < 2048; i += 512) {
        int m = i >> 7, k = i & 127;
        sH[0][m * 136 + k] = (_Float16)h0[(size_t)(b0 + m) * 128 + k];
    }
    for (int i = tid; i < 1024; i += 512) {
        int bb = i >> 9, rem = i & 511;
        int m = rem >> 5, c = 40 + (rem & 31);
        sX[bb][m * 72 + c] = (_Float16)0.f;
    }
    const bool stx = tid < 160;
    const int sm = tid / 10, sc = tid - sm * 10;
    if (stx) *(uint2*)(&sX[0][sm * 72 + sc * 4]) =
        *(const uint2*)(feat + (size_t)(b0 + sm) * 40 + sc * 4);
    if (tid < 16) sDm[0][tid] = 1.f - done[b0 + tid];

    uint2 xrA = {0, 0}, xrB = {0, 0};
    float drA = 0.f, drB = 0.f;
    if (stx) xrA = *(const uint2*)(feat + ((size_t)B_ + b0 + sm) * 40 + sc * 4);
    if (tid < 16) drA = done[(size_t)B_ + b0 + tid];

    const _Float16* fptr = feat + ((size_t)2 * B_ + b0 + sm) * 40 + sc * 4;
    const float* dptr = done + (size_t)2 * B_ + b0 + tid;
    float* hq = hid + (size_t)b0 * 128 + j;

    __syncthreads();

    for (int t = 0; t < T_; ++t) {
        const int p = t & 1;
        const bool pf1 = (t + 1 < T_);
        const bool pf2 = (t + 2 < T_);

        if (stx && pf1) *(uint2*)(&sX[1 - p][sm * 72 + sc * 4]) = xrA;
        if (tid < 16 && pf1) sDm[1 - p][tid] = 1.f - drA;

        if (stx && pf2) xrB = *(const uint2*)fptr;
        if (tid < 16 && pf2) drB = dptr[0];
        fptr += (size_t)B_ * 40;
        dptr += B_;

        if (t > 0) {
            #pragma unroll
            for (int r = 0; r < 4; ++r)
                hq[(size_t)(lq * 4 + r) * 128] = hl[r];
            hq += (size_t)B_ * 128;
        }

        const f32x4 dmv = *(const f32x4*)&sDm[p][lq * 4];
        const float dml = sDm[p][lr];
        const bool keep = (dml != 0.f);

        f32x4 acc[4];
        #pragma unroll
        for (int g = 0; g < 4; ++g)
            acc[g] = (f32x4){bias[g], bias[g], bias[g], bias[g]};

        {
            half8 x0 = *(const half8*)&sX[p][lr * 72 + lq * 8];
            half8 x1 = *(const half8*)&sX[p][lr * 72 + 32 + lq * 8];
            #pragma unroll
            for (int g = 0; g < 4; ++g) acc[g] = MFMA16(x0, wfr[g][0], acc[g]);
            #pragma unroll
            for (int g = 0; g < 4; ++g) acc[g] = MFMA16(x0, wfr[g][6], acc[g]);
            #pragma unroll
            for (int g = 0; g < 4; ++g) acc[g] = MFMA16(x1, wfr[g][1], acc[g]);
            #pragma unroll
            for (int g = 0; g < 4; ++g) acc[g] = MFMA16(x1, wfr[g][7], acc[g]);
        }

        #pragma unroll
        for (int u = 0; u < 4; ++u) {
            half8 av = *(const half8*)&sH[p][lr * 136 + u * 32 + lq * 8];
            av = keep ? av : hz;
            #pragma unroll
            for (int g = 0; g < 4; ++g) acc[g] = MFMA16(av, wfr[g][2 + u], acc[g]);
            #pragma unroll
            for (int g = 0; g < 4; ++g) acc[g] = MFMA16(av, wfr[g][8 + u], acc[g]);
        }

        #pragma unroll
        for (int r = 0; r < 4; ++r) {
            const int m = lq * 4 + r;
            float iv = sigm_(acc[0][r]);
            float fv = sigm_(acc[1][r]);
            float gv = tanh_(acc[2][r]);
            float ov = sigm_(acc[3][r]);
            float cn = fv * (cc[r] * dmv[r]) + iv * gv;
            float hv = ov * tanh_(cn);
            cc[r] = cn;
            hl[r] = hv;
            sH[1 - p][m * 136 + j] = (_Float16)hv;
        }

        lds_barrier();
        xrA = xrB;
        drA = drB;
    }

    #pragma unroll
    for (int r = 0; r < 4; ++r) {
        hq[(size_t)(lq * 4 + r) * 128] = hl[r];
        hN[(size_t)(b0 + lq * 4 + r) * 128 + j] = hl[r];
        cN[(size_t)(b0 + lq * 4 + r) * 128 + j] = cc[r];
    }
}

// =============== heads: MFMA (R18-validated) — UNCHANGED ===============
__global__ __launch_bounds__(256)
void k_heads(const float* __restrict__ hidden, const _Float16* __restrict__ wsh,
             const float* __restrict__ bcomb, float* __restrict__ oact,
             float* __restrict__ omsg, float* __restrict__ oval) {
    __shared__ __align__(16) _Float16 sHd[64 * 136];
    const int tid = threadIdx.x;
    const int w = tid >> 6, lane = tid & 63;
    const int lq = lane >> 4, lr = lane & 15;
    const int rowbase = blockIdx.x * 64;

    {
        const int m = tid >> 2, q = tid & 3;
        const float* src = hidden + (size_t)(rowbase + m) * 128 + q * 32;
        #pragma unroll
        for (int s = 0; s < 4; ++s) {
            f32x4 a = *(const f32x4*)(src + s * 8);
            f32x4 b = *(const f32x4*)(src + s * 8 + 4);
            half8 pk;
            #pragma unroll
            for (int e = 0; e < 4; ++e) pk[e] = (_Float16)a[e];
            #pragma unroll
            for (int e = 0; e < 4; ++e) pk[4 + e] = (_Float16)b[e];
            *(half8*)&sHd[m * 136 + q * 32 + s * 8] = pk;
        }
    }
    __syncthreads();

    half8 av[4];
    #pragma unroll
    for (int kt = 0; kt < 4; ++kt)
        av[kt] = *(const half8*)&sHd[(w * 16 + lr) * 136 + kt * 32 + lq * 8];

    const half8* hwp = (const half8*)(wsh + HDW);
    const float* hb = bcomb + 512;
    #pragma unroll
    for (int nt = 0; nt < 2; ++nt) {
        const float b0 = hb[nt * 16 + lr];
        f32x4 hacc = (f32x4){b0, b0, b0, b0};
        #pragma unroll
        for (int kt = 0; kt < 4; ++kt)
            hacc = MFMA16(av[kt], hwp[(nt * 4 + kt) * 64 + lane], hacc);
        const int o = nt * 16 + lr;
        #pragma unroll
        for (int r = 0; r < 4; ++r) {
            const size_t row = (size_t)rowbase + w * 16 + lq * 4 + r;
            float vv = hacc[r];
            if (o < 6)        oact[row * 6 + o] = vv;
            else if (o < 22)  omsg[row * 16 + (o - 6)] = vv;
            else if (o == 22) oval[row] = vv;
        }
    }
}

// =============== launch ===============
extern "C" void kernel_launch(void* const* d_in, const int* in_sizes, int n_in,
                              void* d_out, int out_size, void* d_ws, size_t ws_size,
                              hipStream_t stream) {
    const float* image = (const float*)d_in[0];
    const float* location = (const float*)d_in[1];
    const int*   message = (const int*)d_in[2];
    const float* done = (const float*)d_in[3];
    const float* h0 = (const float*)d_in[4];
    const float* c0 = (const float*)d_in[5];
    const float* vw1 = (const float*)d_in[6];  const float* vb1 = (const float*)d_in[7];
    const float* vw2 = (const float*)d_in[8];  const float* vb2 = (const float*)d_in[9];
    const float* vw3 = (const float*)d_in[10]; const float* vb3 = (const float*)d_in[11];
    const float* vw4 = (const float*)d_in[12]; const float* vb4 = (const float*)d_in[13];
    const float* emb = (const float*)d_in[14];
    const float* mw = (const float*)d_in[15];  const float* mb = (const float*)d_in[16];
    const float* lw = (const float*)d_in[17];  const float* lb = (const float*)d_in[18];
    const float* wih = (const float*)d_in[19]; const float* whh = (const float*)d_in[20];
    const float* bih = (const float*)d_in[21]; const float* bhh = (const float*)d_in[22];
    const float* aw = (const float*)d_in[23];  const float* ab = (const float*)d_in[24];
    const float* cw = (const float*)d_in[25];  const float* cb = (const float*)d_in[26];
    const float* msw = (const float*)d_in[27]; const float* msb = (const float*)d_in[28];

    _Float16* wsh = (_Float16*)d_ws;
    float* bcomb = (float*)((char*)d_ws + WS_HALFS * 2);

    float* out = (float*)d_out;
    float* oh   = out;
    float* oact = out + OUT_ACT;
    float* omsg = out + OUT_MSG;
    float* oval = out + OUT_VAL;
    float* ohN  = out + OUT_HN;
    float* ocN  = out + OUT_CN;

    // merged prep (1 launch)
    k_prep<<<1212, 256, 0, stream>>>(vw1, vw2, vw3, vw4, wih, whh, emb, mw, mb,
                                     bih, bhh, aw, ab, cw, cb, msw, msb,
                                     wsh, bcomb);
    // encoder -> feat f16 [TB,40] (R13-form, 64-row tiles)
    k_encoder<<<TB_ / 64, 256, 0, stream>>>(image, location, message, vb1, vb2, vb3, vb4,
                                            lw, lb, wsh, wsh + FEAT);
    // recurrent scan
    k_lstm8<<<B_ / 16, 512, 0, stream>>>(wsh, bcomb, done, h0, c0, oh, ohN, ocN);
    // heads (MFMA)
    k_heads<<<TB_ / 64, 256, 0, stream>>>(oh, wsh, bcomb, oact, omsg, oval);
}